// Round 7
// baseline (361.350 us; speedup 1.0000x reference)
//
#include <hip/hip_runtime.h>
#include <math.h>
#include <stdint.h>

#define BB    4
#define QQ    200
#define NGT   32
#define DD    65536   // 256*256
#define TOPK  4
#define EPSF  1e-6f
#define QP    208     // padded Q stride

#define QT16  13      // ceil(200/16) q-tiles of 16
#define KG    16      // K-split: wg covers DD/KG = 4096 k
#define KSPAN (DD / KG)       // 4096
#define BK    256             // k per staged chunk (1 KB per row)
#define NCH   (KSPAN / BK)    // 16 chunks
#define NBUF  3               // pipeline depth (LDS buffers)
#define RS    260             // LDS row stride (floats), multiple of 4 for b128 align

typedef float  f32x4  __attribute__((ext_vector_type(4)));
typedef __bf16 bf16x8 __attribute__((ext_vector_type(8)));

// async global->LDS DMA, 16 B/lane: LDS dest = (wave-uniform base) + lane*16
#define GLOAD_LDS16(gp, lp)                                                       \
    __builtin_amdgcn_global_load_lds(                                             \
        (const __attribute__((address_space(1))) void*)(gp),                      \
        (__attribute__((address_space(3))) void*)(lp), 16, 0, 0)

// raw workgroup barrier WITHOUT the compiler's vmcnt(0) drain (the m97 stall).
// memory clobber = compile-time ordering only; HW ordering is our vmcnt waits.
#define RAW_BARRIER() asm volatile("s_barrier" ::: "memory")

// s_waitcnt vmcnt(N), expcnt/lgkmcnt unconstrained.
// gfx9 encoding: vmcnt[3:0]=bits3:0, expcnt=bits6:4, lgkmcnt=bits11:8, vmcnt[5:4]=bits15:14
#define WAIT_VMCNT_8()  __builtin_amdgcn_s_waitcnt(0x0F78)
#define WAIT_VMCNT_10() __builtin_amdgcn_s_waitcnt(0x0F7A)

// ---------------------------------------------------------------------------
// K1: bit-pack gt_masks -> packed[b][d] (bit n = gt[b,n,d]); fused zero-init
// of inter+psum (ws is poisoned 0xAA before every timed call).
__global__ __launch_bounds__(256) void k_pack(const float* __restrict__ gt,
                                              uint32_t* __restrict__ packed,
                                              float* __restrict__ zero_base) {
    int zidx = blockIdx.x * 256 + threadIdx.x;
    if (zidx < BB * NGT * QP + BB * QP) zero_base[zidx] = 0.0f;

    int blk = blockIdx.x;
    int b = blk >> 6;
    int d0 = ((blk & 63) * 256 + threadIdx.x) * 4;
    uint32_t px = 0, py = 0, pz = 0, pw = 0;
    const float* gb = gt + (size_t)b * NGT * DD + d0;
#pragma unroll
    for (int n = 0; n < NGT; ++n) {
        float4 g = *(const float4*)(gb + (size_t)n * DD);
        px |= (g.x > 0.5f ? 1u : 0u) << n;
        py |= (g.y > 0.5f ? 1u : 0u) << n;
        pz |= (g.z > 0.5f ? 1u : 0u) << n;
        pw |= (g.w > 0.5f ? 1u : 0u) << n;
    }
    *(uint4*)(packed + (size_t)b * DD + d0) = make_uint4(px, py, pz, pw);
}

// ---------------------------------------------------------------------------
// K2: tsum[b][n] via popcount of packed bits.
__global__ __launch_bounds__(256) void k_tsum(const uint32_t* __restrict__ packed,
                                              float* __restrict__ tsum) {
    int b = blockIdx.x >> 5;
    int n = blockIdx.x & 31;
    const uint4* pp = (const uint4*)(packed + (size_t)b * DD);
    int cnt = 0;
    for (int i = threadIdx.x; i < DD / 4; i += 256) {
        uint4 w = pp[i];
        cnt += (int)((w.x >> n) & 1u) + (int)((w.y >> n) & 1u) +
               (int)((w.z >> n) & 1u) + (int)((w.w >> n) & 1u);
    }
#pragma unroll
    for (int off = 32; off; off >>= 1) cnt += __shfl_xor(cnt, off);
    __shared__ int red[4];
    if ((threadIdx.x & 63) == 0) red[threadIdx.x >> 6] = cnt;
    __syncthreads();
    if (threadIdx.x == 0)
        tsum[blockIdx.x] = (float)(red[0] + red[1] + red[2] + red[3]);
}

// ---------------------------------------------------------------------------
// K3: MFMA main, 3-deep async-DMA pipeline (AITER-style partial vmcnt).
// Grid = B*QT16*KG wgs of 256 (4 waves). wg = 16 q-rows x 4096 k.
// 3 LDS buffers; chunk c's DMA issued 3 iterations before use (latency
// hidden); per iteration each wave waits only for ITS OWN oldest chunk
// (vmcnt<=2-chunks-in-flight), then raw s_barrier (no vmcnt(0) drain).
// Compute: waves split the 8 32-k steps (2 each); sigmoid + exact 3-term
// bf16 split in-reg; B bits -> bf16 0/1; 6 mfma_f32_16x16x32_bf16 per step.
__global__ __launch_bounds__(256, 3) void k_mfma(const float* __restrict__ pm,
                                                 const uint32_t* __restrict__ packed,
                                                 float* __restrict__ inter,   // [B][32][QP]
                                                 float* __restrict__ psum) {  // [B][QP]
    int blk = blockIdx.x;
    int b   = blk / (QT16 * KG);
    int rem = blk % (QT16 * KG);
    int qt  = rem / KG;
    int kg  = rem % KG;
    int tid = threadIdx.x, lane = tid & 63, wave = tid >> 6;
    int m = lane & 15, quad = lane >> 4;   // A-row / C-col(n) / B-bit = m

    __shared__ float    sA[NBUF][16][RS];   // 49,920 B raw f32 tiles
    __shared__ uint32_t sB[NBUF][BK];       //  3,072 B packed bits

    const size_t kbase = (size_t)kg * KSPAN;
    const float*    pmb = pm + (size_t)b * QQ * DD + kbase;
    const uint32_t* pkb = packed + (size_t)b * DD + kbase;

    auto stage = [&](int c, int bf) {
#pragma unroll
        for (int i = 0; i < 4; ++i) {
            int row = wave * 4 + i;
            int qg  = qt * 16 + row;
            int qe  = qg < QQ ? qg : QQ - 1;          // clamped rows: L2 hits
            const float* gp = pmb + (size_t)qe * DD + c * BK + lane * 4;
            GLOAD_LDS16(gp, &sA[bf][row][0]);
        }
        if (wave == 0) {
            const uint32_t* gp = pkb + c * BK + lane * 4;
            GLOAD_LDS16(gp, &sB[bf][0]);
        }
    };

    f32x4 cH0 = {0.f,0.f,0.f,0.f}, cL0 = {0.f,0.f,0.f,0.f};
    f32x4 cH1 = {0.f,0.f,0.f,0.f}, cL1 = {0.f,0.f,0.f,0.f};
    float ps = 0.f;

    stage(0, 0);
    stage(1, 1);
    stage(2, 2);

    for (int c = 0; c < NCH; ++c) {
        // wait for OWN chunk-c loads: <= 2 chunks (8 loads; wave0 also has sB)
        if (wave == 0) WAIT_VMCNT_10(); else WAIT_VMCNT_8();
        RAW_BARRIER();                 // all waves' chunk-c DMA landed
        int bf = c % NBUF;
#pragma unroll
        for (int st = 0; st < 2; ++st) {
            int k0 = (wave * 2 + st) * 32 + quad * 8;
            float4 a0 = *(const float4*)&sA[bf][m][k0];
            float4 a1 = *(const float4*)&sA[bf][m][k0 + 4];
            uint4  w0 = *(const uint4*)&sB[bf][k0];
            uint4  w1 = *(const uint4*)&sB[bf][k0 + 4];

            // A: sigmoid + exact 3-term split (hi/mid/lo bit-truncation)
            float xs[8] = {a0.x, a0.y, a0.z, a0.w, a1.x, a1.y, a1.z, a1.w};
            uint32_t hu[8], mu[8], lu[8];
#pragma unroll
            for (int i = 0; i < 8; ++i) {
                float x  = xs[i];
                float sg = __builtin_amdgcn_rcpf(1.0f + __expf(-x));
                ps += sg;
                uint32_t u0 = __float_as_uint(sg);
                float hi = __uint_as_float(u0 & 0xFFFF0000u);
                float r1 = sg - hi;                      // exact
                uint32_t u1 = __float_as_uint(r1);
                float mi = __uint_as_float(u1 & 0xFFFF0000u);
                float r2 = r1 - mi;                      // exact, <=8 sig bits
                hu[i] = u0; mu[i] = u1; lu[i] = __float_as_uint(r2);
            }
            union { uint4 u; bf16x8 v; } ah, am, al;
            ah.u = make_uint4((hu[0] >> 16) | (hu[1] & 0xFFFF0000u),
                              (hu[2] >> 16) | (hu[3] & 0xFFFF0000u),
                              (hu[4] >> 16) | (hu[5] & 0xFFFF0000u),
                              (hu[6] >> 16) | (hu[7] & 0xFFFF0000u));
            am.u = make_uint4((mu[0] >> 16) | (mu[1] & 0xFFFF0000u),
                              (mu[2] >> 16) | (mu[3] & 0xFFFF0000u),
                              (mu[4] >> 16) | (mu[5] & 0xFFFF0000u),
                              (mu[6] >> 16) | (mu[7] & 0xFFFF0000u));
            al.u = make_uint4((lu[0] >> 16) | (lu[1] & 0xFFFF0000u),
                              (lu[2] >> 16) | (lu[3] & 0xFFFF0000u),
                              (lu[4] >> 16) | (lu[5] & 0xFFFF0000u),
                              (lu[6] >> 16) | (lu[7] & 0xFFFF0000u));

            // B: bits m (n=0..15) and 16+m (n=16..31) of 8 words -> bf16 0/1
            uint32_t wj[8] = {w0.x, w0.y, w0.z, w0.w, w1.x, w1.y, w1.z, w1.w};
            union { ushort u[8]; bf16x8 v; } b0, b1;
#pragma unroll
            for (int j = 0; j < 8; ++j) {
                b0.u[j] = (ushort)((((int)(wj[j] << (31 - m))) >> 31) & 0x3F80);
                b1.u[j] = (ushort)((((int)(wj[j] << (15 - m))) >> 31) & 0x3F80);
            }

            cH0 = __builtin_amdgcn_mfma_f32_16x16x32_bf16(ah.v, b0.v, cH0, 0, 0, 0);
            cL0 = __builtin_amdgcn_mfma_f32_16x16x32_bf16(am.v, b0.v, cL0, 0, 0, 0);
            cL0 = __builtin_amdgcn_mfma_f32_16x16x32_bf16(al.v, b0.v, cL0, 0, 0, 0);
            cH1 = __builtin_amdgcn_mfma_f32_16x16x32_bf16(ah.v, b1.v, cH1, 0, 0, 0);
            cL1 = __builtin_amdgcn_mfma_f32_16x16x32_bf16(am.v, b1.v, cL1, 0, 0, 0);
            cL1 = __builtin_amdgcn_mfma_f32_16x16x32_bf16(al.v, b1.v, cL1, 0, 0, 0);
        }
        RAW_BARRIER();                 // all waves done reading buf before refill
        if (c + NBUF < NCH) stage(c + NBUF, bf);
    }

    // psum: lanes m, m+16, m+32, m+48 share q-row m (per wave, own k-slice)
    ps += __shfl_xor(ps, 16);
    ps += __shfl_xor(ps, 32);
    if (lane < 16) {
        int qg = qt * 16 + m;
        if (qg < QQ) atomicAdd(&psum[b * QP + qg], ps);
    }

    // cross-wave C reduce in LDS (stride 9: gcd(9,32)=1), one atomic set/wg.
    float c8[8];
#pragma unroll
    for (int r = 0; r < 4; ++r) {
        c8[r]     = cH0[r] + cL0[r];
        c8[4 + r] = cH1[r] + cL1[r];
    }
    __syncthreads();                   // full drain OK here (once per kernel)
    float* cred = (float*)sA;
    if (wave > 0) {
        float* dst = cred + ((wave - 1) * 64 + lane) * 9;
#pragma unroll
        for (int r = 0; r < 8; ++r) dst[r] = c8[r];
    }
    __syncthreads();
    if (wave == 0) {
#pragma unroll
        for (int wv = 0; wv < 3; ++wv) {
            const float* sp = cred + (wv * 64 + lane) * 9;
#pragma unroll
            for (int r = 0; r < 8; ++r) c8[r] += sp[r];
        }
        // C layout (16x16, m89): col(n) = lane&15, row(q) = quad*4 + r
#pragma unroll
        for (int r = 0; r < 4; ++r) {
            int qg = qt * 16 + quad * 4 + r;
            if (qg < QQ) {
                atomicAdd(&inter[(b * NGT + m) * QP + qg],      c8[r]);
                atomicAdd(&inter[(b * NGT + 16 + m) * QP + qg], c8[4 + r]);
            }
        }
    }
}

// ---------------------------------------------------------------------------
// K4: parallel top-4 per (b,n); combined = iou*cls computed on the fly.
__global__ __launch_bounds__(64) void k_topk(const float* __restrict__ inter,
                                             const float* __restrict__ psum,
                                             const float* __restrict__ tsum,
                                             const float* __restrict__ logits,
                                             int* __restrict__ idx4) {
    int bn = blockIdx.x;            // b*32 + n
    int b  = bn >> 5;
    int lane = threadIdx.x;
    float tsn = tsum[bn];
    float v[4];
#pragma unroll
    for (int s = 0; s < 4; ++s) {
        int q = lane + 64 * s;
        if (q < QQ) {
            float iv = inter[(size_t)bn * QP + q];
            float un = psum[b * QP + q] + tsn - iv;
            float l0 = logits[(b * QQ + q) * 2];
            float l1 = logits[(b * QQ + q) * 2 + 1];
            float cl = 1.0f / (1.0f + expf(l0 - l1));
            v[s] = iv / (un + EPSF) * cl;
        } else {
            v[s] = -INFINITY;
        }
    }
    for (int k = 0; k < TOPK; ++k) {
        float bv = -INFINITY;
        int   bi = 0x7fffffff;
#pragma unroll
        for (int s = 0; s < 4; ++s)
            if (v[s] > bv) { bv = v[s]; bi = lane + 64 * s; }
#pragma unroll
        for (int off = 32; off; off >>= 1) {
            float ov = __shfl_xor(bv, off);
            int   oi = __shfl_xor(bi, off);
            if (ov > bv || (ov == bv && oi < bi)) { bv = ov; bi = oi; }
        }
        if (lane == (bi & 63)) v[bi >> 6] = -INFINITY;
        if (lane == 0) idx4[bn * TOPK + k] = bi;
    }
}

// ---------------------------------------------------------------------------
// K5: sequential dedup over GTs (indices precomputed). One wave per b.
__global__ __launch_bounds__(64) void k_final(const int* __restrict__ idx4,
                                              int* __restrict__ out) {
    int b = blockIdx.x;
    int lane = threadIdx.x;
    int* src = out;
    int* tgt = out + BB * NGT * TOPK;
    int* val = out + 2 * BB * NGT * TOPK;
    int asg = 0;   // 4 assigned bits: q = lane + 64*slot
    for (int n = 0; n < NGT; ++n) {
        int4 id = *(const int4*)&idx4[(b * NGT + n) * TOPK];
        int ids[4] = {id.x, id.y, id.z, id.w};
        int newasg = asg;
#pragma unroll
        for (int k = 0; k < TOPK; ++k) {
            int idx = ids[k];                      // uniform across lanes
            int owner = idx & 63, slot = idx >> 6;
            int oasg = __shfl(asg, owner);         // pre-n state (idx distinct in n)
            int taken = (oasg >> slot) & 1;
            if (lane == owner) newasg |= (1 << slot);
            if (lane == 0) {
                int o = (b * NGT + n) * TOPK + k;
                src[o] = taken ? -1 : idx;
                tgt[o] = taken ? -1 : n;
                val[o] = taken ? 0 : 1;
            }
        }
        asg = newasg;
    }
}

// ---------------------------------------------------------------------------
extern "C" void kernel_launch(void* const* d_in, const int* in_sizes, int n_in,
                              void* d_out, int out_size, void* d_ws, size_t ws_size,
                              hipStream_t stream) {
    const float* pred_masks  = (const float*)d_in[0];  // [4,200,256,256]
    const float* pred_logits = (const float*)d_in[1];  // [4,200,2]
    const float* gt_masks    = (const float*)d_in[2];  // [4,32,256,256]

    uint8_t* ws = (uint8_t*)d_ws;
    uint32_t* packed = (uint32_t*)ws;                   // 1 MB
    float* tsum  = (float*)(ws + (size_t)BB * DD * 4);  // 128
    float* inter = tsum + BB * NGT;                     // 26624 (zeroed by k_pack)
    float* psum  = inter + BB * NGT * QP;               // 832   (zeroed, contiguous)
    int*   idx4  = (int*)(psum + BB * QP);              // 512

    k_pack <<<BB * (DD / 1024), 256, 0, stream>>>(gt_masks, packed, inter);
    k_tsum <<<BB * NGT,         256, 0, stream>>>(packed, tsum);
    k_mfma <<<BB * QT16 * KG,   256, 0, stream>>>(pred_masks, packed, inter, psum);
    k_topk <<<BB * NGT,          64, 0, stream>>>(inter, psum, tsum, pred_logits, idx4);
    k_final<<<BB,                64, 0, stream>>>(idx4, (int*)d_out);
}

// Round 8
// 352.812 us; speedup vs baseline: 1.0242x; 1.0242x over previous
//
#include <hip/hip_runtime.h>
#include <math.h>
#include <stdint.h>

#define BB    4
#define QQ    200
#define NGT   32
#define DD    65536   // 256*256
#define TOPK  4
#define EPSF  1e-6f
#define QP    208     // padded Q stride

#define QT16  13      // ceil(200/16) q-tiles of 16
#define KG    16      // K-split: wg covers DD/KG = 4096 k
#define KSPAN (DD / KG)       // 4096
#define BK    512             // k per staged chunk (2 KB per row)
#define NCH   (KSPAN / BK)    // 8 chunks
#define RS    516             // LDS row stride (floats): 16B-aligned, spreads bank-quads

typedef float  f32x4  __attribute__((ext_vector_type(4)));
typedef __bf16 bf16x8 __attribute__((ext_vector_type(8)));

// raw workgroup barrier WITHOUT the compiler's vmcnt(0) drain.
#define RAW_BARRIER() asm volatile("s_barrier" ::: "memory")
// LDS write visibility before barrier: lgkm only, never vm.
#define LGKM_DRAIN()  asm volatile("s_waitcnt lgkmcnt(0)" ::: "memory")

// ---------------------------------------------------------------------------
// K1: bit-pack gt_masks -> packed[b][d] (bit n = gt[b,n,d]); fused zero-init
// of inter+psum (ws is poisoned 0xAA before every timed call).
__global__ __launch_bounds__(256) void k_pack(const float* __restrict__ gt,
                                              uint32_t* __restrict__ packed,
                                              float* __restrict__ zero_base) {
    int zidx = blockIdx.x * 256 + threadIdx.x;
    if (zidx < BB * NGT * QP + BB * QP) zero_base[zidx] = 0.0f;

    int blk = blockIdx.x;
    int b = blk >> 6;
    int d0 = ((blk & 63) * 256 + threadIdx.x) * 4;
    uint32_t px = 0, py = 0, pz = 0, pw = 0;
    const float* gb = gt + (size_t)b * NGT * DD + d0;
#pragma unroll
    for (int n = 0; n < NGT; ++n) {
        float4 g = *(const float4*)(gb + (size_t)n * DD);
        px |= (g.x > 0.5f ? 1u : 0u) << n;
        py |= (g.y > 0.5f ? 1u : 0u) << n;
        pz |= (g.z > 0.5f ? 1u : 0u) << n;
        pw |= (g.w > 0.5f ? 1u : 0u) << n;
    }
    *(uint4*)(packed + (size_t)b * DD + d0) = make_uint4(px, py, pz, pw);
}

// ---------------------------------------------------------------------------
// K2: tsum[b][n] via popcount of packed bits (1 MB, L2/L3-resident).
__global__ __launch_bounds__(256) void k_tsum(const uint32_t* __restrict__ packed,
                                              float* __restrict__ tsum) {
    int b = blockIdx.x >> 5;
    int n = blockIdx.x & 31;
    const uint4* pp = (const uint4*)(packed + (size_t)b * DD);
    int cnt = 0;
    for (int i = threadIdx.x; i < DD / 4; i += 256) {
        uint4 w = pp[i];
        cnt += (int)((w.x >> n) & 1u) + (int)((w.y >> n) & 1u) +
               (int)((w.z >> n) & 1u) + (int)((w.w >> n) & 1u);
    }
#pragma unroll
    for (int off = 32; off; off >>= 1) cnt += __shfl_xor(cnt, off);
    __shared__ int red[4];
    if ((threadIdx.x & 63) == 0) red[threadIdx.x >> 6] = cnt;
    __syncthreads();
    if (threadIdx.x == 0)
        tsum[blockIdx.x] = (float)(red[0] + red[1] + red[2] + red[3]);
}

// ---------------------------------------------------------------------------
// K3: MFMA main, VGPR-staged (m13-grade load path), phase-shifted pipeline.
// Grid = B*QT16*KG = 832 wgs of 256 (4 waves) -> 4 wgs/CU, ALL resident.
// Per 512-k chunk: each wave issues 8 float4 loads, each = ONE row's 1-KB
// contiguous run (per-instr coalescing like m13's 6.3 TB/s copy), results
// held in registers across compute(c), then ds_write. Loads for c+1 issue at
// the TOP of compute(c) (~1100 cy lead > 900 cy HBM latency), so the
// compiler's partial-vmcnt waits in the write phase are pre-satisfied.
// Barriers: raw s_barrier + lgkmcnt(0) only (no vm drain anywhere in-loop).
__global__ __launch_bounds__(256, 4) void k_mfma(const float* __restrict__ pm,
                                                 const uint32_t* __restrict__ packed,
                                                 float* __restrict__ inter,   // [B][32][QP]
                                                 float* __restrict__ psum) {  // [B][QP]
    int blk = blockIdx.x;
    int b   = blk / (QT16 * KG);
    int rem = blk % (QT16 * KG);
    int qt  = rem / KG;
    int kg  = rem % KG;
    int tid = threadIdx.x, lane = tid & 63, wave = tid >> 6;
    int m = lane & 15, quad = lane >> 4;   // m: A-row / C-col(n) / B-bit

    __shared__ float    sA[16][RS];   // 33 KB
    __shared__ uint32_t sBw[BK];      //  2 KB

    const float*    pmb = pm + (size_t)b * QQ * DD + (size_t)kg * KSPAN;
    const uint32_t* pkb = packed + (size_t)b * DD + (size_t)kg * KSPAN;

    int row0 = wave * 4;               // this wave stages rows row0..row0+3
    int qrow[4];
#pragma unroll
    for (int i = 0; i < 4; ++i) {
        int qg = qt * 16 + row0 + i;
        qrow[i] = qg < QQ ? qg : QQ - 1;   // clamped rows masked at output
    }

    float4 ra[8];   // 4 rows x 2 segments of 1 KB
    uint2  rb;      // B bits: thread covers sBw[tid*2 .. +2)

    // ---- prologue: load + write chunk 0
#pragma unroll
    for (int i = 0; i < 4; ++i) {
        const float* rp = pmb + (size_t)qrow[i] * DD + lane * 4;
        ra[2 * i]     = *(const float4*)(rp);
        ra[2 * i + 1] = *(const float4*)(rp + 256);
    }
    rb = *(const uint2*)(pkb + tid * 2);
#pragma unroll
    for (int i = 0; i < 4; ++i) {
        *(float4*)&sA[row0 + i][lane * 4]       = ra[2 * i];
        *(float4*)&sA[row0 + i][256 + lane * 4] = ra[2 * i + 1];
    }
    *(uint2*)&sBw[tid * 2] = rb;
    LGKM_DRAIN();
    RAW_BARRIER();

    f32x4 cH0 = {0.f,0.f,0.f,0.f}, cL0 = {0.f,0.f,0.f,0.f};
    f32x4 cH1 = {0.f,0.f,0.f,0.f}, cL1 = {0.f,0.f,0.f,0.f};
    float ps = 0.f;

    for (int c = 0; c < NCH; ++c) {
        // prefetch chunk c+1 into registers (issued before compute)
        if (c + 1 < NCH) {
            const float* base = pmb + (size_t)(c + 1) * BK;
#pragma unroll
            for (int i = 0; i < 4; ++i) {
                const float* rp = base + (size_t)qrow[i] * DD + lane * 4;
                ra[2 * i]     = *(const float4*)(rp);
                ra[2 * i + 1] = *(const float4*)(rp + 256);
            }
            rb = *(const uint2*)(pkb + (size_t)(c + 1) * BK + tid * 2);
        }

        // compute chunk c: wave covers k in [wave*128, wave*128+128)
#pragma unroll
        for (int st = 0; st < 4; ++st) {
            int k0 = (wave * 4 + st) * 32 + quad * 8;
            float4 a0 = *(const float4*)&sA[m][k0];
            float4 a1 = *(const float4*)&sA[m][k0 + 4];
            uint4  w0 = *(const uint4*)&sBw[k0];
            uint4  w1 = *(const uint4*)&sBw[k0 + 4];

            // A: sigmoid + exact 3-term split (hi/mid/lo bit-truncation)
            float xs[8] = {a0.x, a0.y, a0.z, a0.w, a1.x, a1.y, a1.z, a1.w};
            uint32_t hu[8], mu[8], lu[8];
#pragma unroll
            for (int i = 0; i < 8; ++i) {
                float x  = xs[i];
                float sg = __builtin_amdgcn_rcpf(1.0f + __expf(-x));
                ps += sg;
                uint32_t u0 = __float_as_uint(sg);
                float hi = __uint_as_float(u0 & 0xFFFF0000u);
                float r1 = sg - hi;                      // exact
                uint32_t u1 = __float_as_uint(r1);
                float mi = __uint_as_float(u1 & 0xFFFF0000u);
                float r2 = r1 - mi;                      // exact, <=8 sig bits
                hu[i] = u0; mu[i] = u1; lu[i] = __float_as_uint(r2);
            }
            union { uint4 u; bf16x8 v; } ah, am, al;
            ah.u = make_uint4((hu[0] >> 16) | (hu[1] & 0xFFFF0000u),
                              (hu[2] >> 16) | (hu[3] & 0xFFFF0000u),
                              (hu[4] >> 16) | (hu[5] & 0xFFFF0000u),
                              (hu[6] >> 16) | (hu[7] & 0xFFFF0000u));
            am.u = make_uint4((mu[0] >> 16) | (mu[1] & 0xFFFF0000u),
                              (mu[2] >> 16) | (mu[3] & 0xFFFF0000u),
                              (mu[4] >> 16) | (mu[5] & 0xFFFF0000u),
                              (mu[6] >> 16) | (mu[7] & 0xFFFF0000u));
            al.u = make_uint4((lu[0] >> 16) | (lu[1] & 0xFFFF0000u),
                              (lu[2] >> 16) | (lu[3] & 0xFFFF0000u),
                              (lu[4] >> 16) | (lu[5] & 0xFFFF0000u),
                              (lu[6] >> 16) | (lu[7] & 0xFFFF0000u));

            // B: bits m (n=0..15) and 16+m (n=16..31) of 8 words -> bf16 0/1
            uint32_t wj[8] = {w0.x, w0.y, w0.z, w0.w, w1.x, w1.y, w1.z, w1.w};
            union { ushort u[8]; bf16x8 v; } b0, b1;
#pragma unroll
            for (int j = 0; j < 8; ++j) {
                b0.u[j] = (ushort)((((int)(wj[j] << (31 - m))) >> 31) & 0x3F80);
                b1.u[j] = (ushort)((((int)(wj[j] << (15 - m))) >> 31) & 0x3F80);
            }

            cH0 = __builtin_amdgcn_mfma_f32_16x16x32_bf16(ah.v, b0.v, cH0, 0, 0, 0);
            cL0 = __builtin_amdgcn_mfma_f32_16x16x32_bf16(am.v, b0.v, cL0, 0, 0, 0);
            cL0 = __builtin_amdgcn_mfma_f32_16x16x32_bf16(al.v, b0.v, cL0, 0, 0, 0);
            cH1 = __builtin_amdgcn_mfma_f32_16x16x32_bf16(ah.v, b1.v, cH1, 0, 0, 0);
            cL1 = __builtin_amdgcn_mfma_f32_16x16x32_bf16(am.v, b1.v, cL1, 0, 0, 0);
            cL1 = __builtin_amdgcn_mfma_f32_16x16x32_bf16(al.v, b1.v, cL1, 0, 0, 0);
        }

        RAW_BARRIER();                 // all waves done reading sA/sBw
        if (c + 1 < NCH) {
#pragma unroll
            for (int i = 0; i < 4; ++i) {
                *(float4*)&sA[row0 + i][lane * 4]       = ra[2 * i];
                *(float4*)&sA[row0 + i][256 + lane * 4] = ra[2 * i + 1];
            }
            *(uint2*)&sBw[tid * 2] = rb;
            LGKM_DRAIN();
        }
        RAW_BARRIER();                 // writes visible
    }

    // psum: lanes m, m+16, m+32, m+48 share q-row m (disjoint k)
    ps += __shfl_xor(ps, 16);
    ps += __shfl_xor(ps, 32);
    if (lane < 16) {
        int qg = qt * 16 + m;
        if (qg < QQ) atomicAdd(&psum[b * QP + qg], ps);
    }

    // cross-wave C reduce in LDS (stride 9: gcd(9,32)=1), one atomic set/wg.
    float c8[8];
#pragma unroll
    for (int r = 0; r < 4; ++r) {
        c8[r]     = cH0[r] + cL0[r];
        c8[4 + r] = cH1[r] + cL1[r];
    }
    __syncthreads();                   // full drain OK here (once per kernel)
    float* cred = (float*)sA;
    if (wave > 0) {
        float* dst = cred + ((wave - 1) * 64 + lane) * 9;
#pragma unroll
        for (int r = 0; r < 8; ++r) dst[r] = c8[r];
    }
    __syncthreads();
    if (wave == 0) {
#pragma unroll
        for (int wv = 0; wv < 3; ++wv) {
            const float* sp = cred + (wv * 64 + lane) * 9;
#pragma unroll
            for (int r = 0; r < 8; ++r) c8[r] += sp[r];
        }
        // C layout (16x16, m89): col(n) = lane&15, row(q) = quad*4 + r
#pragma unroll
        for (int r = 0; r < 4; ++r) {
            int qg = qt * 16 + quad * 4 + r;
            if (qg < QQ) {
                atomicAdd(&inter[(b * NGT + m) * QP + qg],      c8[r]);
                atomicAdd(&inter[(b * NGT + 16 + m) * QP + qg], c8[4 + r]);
            }
        }
    }
}

// ---------------------------------------------------------------------------
// K4: parallel top-4 per (b,n); combined = iou*cls computed on the fly.
__global__ __launch_bounds__(64) void k_topk(const float* __restrict__ inter,
                                             const float* __restrict__ psum,
                                             const float* __restrict__ tsum,
                                             const float* __restrict__ logits,
                                             int* __restrict__ idx4) {
    int bn = blockIdx.x;            // b*32 + n
    int b  = bn >> 5;
    int lane = threadIdx.x;
    float tsn = tsum[bn];
    float v[4];
#pragma unroll
    for (int s = 0; s < 4; ++s) {
        int q = lane + 64 * s;
        if (q < QQ) {
            float iv = inter[(size_t)bn * QP + q];
            float un = psum[b * QP + q] + tsn - iv;
            float l0 = logits[(b * QQ + q) * 2];
            float l1 = logits[(b * QQ + q) * 2 + 1];
            float cl = 1.0f / (1.0f + expf(l0 - l1));
            v[s] = iv / (un + EPSF) * cl;
        } else {
            v[s] = -INFINITY;
        }
    }
    for (int k = 0; k < TOPK; ++k) {
        float bv = -INFINITY;
        int   bi = 0x7fffffff;
#pragma unroll
        for (int s = 0; s < 4; ++s)
            if (v[s] > bv) { bv = v[s]; bi = lane + 64 * s; }
#pragma unroll
        for (int off = 32; off; off >>= 1) {
            float ov = __shfl_xor(bv, off);
            int   oi = __shfl_xor(bi, off);
            if (ov > bv || (ov == bv && oi < bi)) { bv = ov; bi = oi; }
        }
        if (lane == (bi & 63)) v[bi >> 6] = -INFINITY;
        if (lane == 0) idx4[bn * TOPK + k] = bi;
    }
}

// ---------------------------------------------------------------------------
// K5: sequential dedup over GTs (indices precomputed). One wave per b.
__global__ __launch_bounds__(64) void k_final(const int* __restrict__ idx4,
                                              int* __restrict__ out) {
    int b = blockIdx.x;
    int lane = threadIdx.x;
    int* src = out;
    int* tgt = out + BB * NGT * TOPK;
    int* val = out + 2 * BB * NGT * TOPK;
    int asg = 0;   // 4 assigned bits: q = lane + 64*slot
    for (int n = 0; n < NGT; ++n) {
        int4 id = *(const int4*)&idx4[(b * NGT + n) * TOPK];
        int ids[4] = {id.x, id.y, id.z, id.w};
        int newasg = asg;
#pragma unroll
        for (int k = 0; k < TOPK; ++k) {
            int idx = ids[k];                      // uniform across lanes
            int owner = idx & 63, slot = idx >> 6;
            int oasg = __shfl(asg, owner);         // pre-n state (idx distinct in n)
            int taken = (oasg >> slot) & 1;
            if (lane == owner) newasg |= (1 << slot);
            if (lane == 0) {
                int o = (b * NGT + n) * TOPK + k;
                src[o] = taken ? -1 : idx;
                tgt[o] = taken ? -1 : n;
                val[o] = taken ? 0 : 1;
            }
        }
        asg = newasg;
    }
}

// ---------------------------------------------------------------------------
extern "C" void kernel_launch(void* const* d_in, const int* in_sizes, int n_in,
                              void* d_out, int out_size, void* d_ws, size_t ws_size,
                              hipStream_t stream) {
    const float* pred_masks  = (const float*)d_in[0];  // [4,200,256,256]
    const float* pred_logits = (const float*)d_in[1];  // [4,200,2]
    const float* gt_masks    = (const float*)d_in[2];  // [4,32,256,256]

    uint8_t* ws = (uint8_t*)d_ws;
    uint32_t* packed = (uint32_t*)ws;                   // 1 MB
    float* tsum  = (float*)(ws + (size_t)BB * DD * 4);  // 128
    float* inter = tsum + BB * NGT;                     // 26624 (zeroed by k_pack)
    float* psum  = inter + BB * NGT * QP;               // 832   (zeroed, contiguous)
    int*   idx4  = (int*)(psum + BB * QP);              // 512

    k_pack <<<BB * (DD / 1024), 256, 0, stream>>>(gt_masks, packed, inter);
    k_tsum <<<BB * NGT,         256, 0, stream>>>(packed, tsum);
    k_mfma <<<BB * QT16 * KG,   256, 0, stream>>>(pred_masks, packed, inter, psum);
    k_topk <<<BB * NGT,          64, 0, stream>>>(inter, psum, tsum, pred_logits, idx4);
    k_final<<<BB,                64, 0, stream>>>(idx4, (int*)d_out);
}